// Round 2
// baseline (320.564 us; speedup 1.0000x reference)
//
#include <hip/hip_runtime.h>
#include <math.h>

#define NCONF  64
#define NATOMS 256
#define NCOEFF 45
#define NAOV   12
#define NPAIR  66
#define RAD    384    // 12 * 32
#define ANG    4224   // 66 * 64
#define TOT    4608
#define APB    8      // atoms per block -> 2048 blocks = one full resident pass

// triu_indices(12, k=1), i-major order
__constant__ unsigned char c_iu[NPAIR] = {
    0,0,0,0,0,0,0,0,0,0,0,
    1,1,1,1,1,1,1,1,1,1,
    2,2,2,2,2,2,2,2,2,
    3,3,3,3,3,3,3,3,
    4,4,4,4,4,4,4,
    5,5,5,5,5,5,
    6,6,6,6,6,
    7,7,7,7,
    8,8,8,
    9,9,
    10
};
__constant__ unsigned char c_ju[NPAIR] = {
    1,2,3,4,5,6,7,8,9,10,11,
    2,3,4,5,6,7,8,9,10,11,
    3,4,5,6,7,8,9,10,11,
    4,5,6,7,8,9,10,11,
    5,6,7,8,9,10,11,
    6,7,8,9,10,11,
    7,8,9,10,11,
    8,9,10,11,
    9,10,11,
    10,11,
    11
};

// linspace(0.5, 3.5, 16); shfR == shfS (same bounds, same eta=16) -> fold with &15
__constant__ float c_shfS[16] = {
    0.5f, 0.7f, 0.9f, 1.1f, 1.3f, 1.5f, 1.7f, 1.9f,
    2.1f, 2.3f, 2.5f, 2.7f, 2.9f, 3.1f, 3.3f, 3.5f
};
// linspace(0.5, 3.5, 8)
__constant__ float c_shfA[8] = {
    0.5f, 0.92857142857f, 1.35714285714f, 1.78571428571f,
    2.21428571429f, 2.64285714286f, 3.07142857143f, 3.5f
};
// cos/sin of shfZ = pi/16 + k*pi/8; cos(acos(c)-z) = c*cosZ + sqrt(1-c^2)*sinZ
__constant__ float c_cosZ[8] = {
     0.98078528f,  0.83146961f,  0.55557023f,  0.19509032f,
    -0.19509032f, -0.55557023f, -0.83146961f, -0.98078528f
};
__constant__ float c_sinZ[8] = {
    0.19509032f, 0.55557023f, 0.83146961f, 0.98078528f,
    0.98078528f, 0.83146961f, 0.55557023f, 0.19509032f
};

__global__ __launch_bounds__(256, 8)
void OrbitalAEVComputer_40492951667225_kernel(const float* __restrict__ coef,
                                              float* __restrict__ out) {
    const int t = threadIdx.x;

    // double-buffered per-atom staging (~10.4 KB total)
    __shared__ float s_dist[2][NAOV];
    __shared__ float s_nv[2][NAOV][3];
    __shared__ float s_rad[2][NAOV * 16];   // unique radial row (S==R folded)
    __shared__ float s_f1[2][NPAIR * 8];
    __shared__ float s_f2[2][NPAIR * 8];

    const int atom0 = blockIdx.x * APB;

    for (int a = 0; a < APB; ++a) {
        const int buf = a & 1;
        const int atom = atom0 + a;
        const float* c = coef + (size_t)atom * NCOEFF;

        // ---- phase 1: 12 AOV vectors -> dist + unit vector (12 threads) ----
        if (t < NAOV) {
            float x, y, z;
            if (t < 4) {
                x = c[9 + 3 * t]; y = c[10 + 3 * t]; z = c[11 + 3 * t];
            } else {
                int r = (t - 4) >> 1, h = (t - 4) & 1;
                const float* b = c + 21 + 6 * r;
                // d-column permutation [0,2,5,4,3,1] split into two rows of 3
                if (h == 0) { x = b[0]; y = b[2]; z = b[5]; }
                else        { x = b[4]; y = b[3]; z = b[1]; }
            }
            float d = sqrtf(x * x + y * y + z * z);
            bool zm = (fabsf(x) < 1e-12f) && (fabsf(y) < 1e-12f) && (fabsf(z) < 1e-12f);
            float inv = zm ? 0.0f : 1.0f / d;
            s_dist[buf][t] = d;
            s_nv[buf][t][0] = x * inv;
            s_nv[buf][t][1] = y * inv;
            s_nv[buf][t][2] = z * inv;
        }
        __syncthreads();

        // ---- phase 2: all table values. 192 radial + 528 f1 + 528 f2 = 1248 items ----
        for (int idx = t; idx < 1248; idx += 256) {
            if (idx < 192) {
                int p = idx >> 4, k = idx & 15;
                float dd = s_dist[buf][p] - c_shfS[k];
                s_rad[buf][idx] = __expf(-16.0f * dd * dd);
            } else if (idx < 720) {
                int jj = idx - 192;
                int q = jj >> 3, k = jj & 7;
                int i1 = c_iu[q], j1 = c_ju[q];
                float cang = s_nv[buf][i1][0] * s_nv[buf][j1][0]
                           + s_nv[buf][i1][1] * s_nv[buf][j1][1]
                           + s_nv[buf][i1][2] * s_nv[buf][j1][2];
                float c95 = 0.95f * cang;                    // cos(angle)
                float sn  = sqrtf(fmaxf(1.0f - c95 * c95, 0.0f));  // sin(angle) >= 0
                float cosa = fmaf(c95, c_cosZ[k], sn * c_sinZ[k]); // cos(angle - shfZ)
                float x = 0.5f * (1.0f + cosa);
                x = x * x; x = x * x; x = x * x; x = x * x; x = x * x; // ^32
                s_f1[buf][jj] = x;
            } else {
                int jj = idx - 720;
                int q = jj >> 3, k = jj & 7;
                int i1 = c_iu[q], j1 = c_ju[q];
                float avd = 0.5f * (s_dist[buf][i1] + s_dist[buf][j1]);
                float dd = avd - c_shfA[k];
                s_f2[buf][jj] = __expf(-8.0f * dd * dd);
            }
        }
        __syncthreads();

        // ---- phase 3: stream 4608 floats out (1152 float4 stores, pure LDS->global) ----
        float* o = out + (size_t)atom * TOT;
        for (int idx4 = t; idx4 < TOT / 4; idx4 += 256) {
            float4 v;
            if (idx4 < 96) {
                int e = idx4 * 4;
                int p = e >> 5;
                int k0 = e & 31;                       // 0,4,8,...,28
                const float* src = &s_rad[buf][p * 16 + (k0 & 15)]; // 16B aligned, in-row
                v = *reinterpret_cast<const float4*>(src);
            } else {
                int e = (idx4 - 96) * 4;               // 0..4223
                int q = e >> 6;
                int z = (e >> 3) & 7;
                int a0 = e & 7;                        // 0 or 4
                float f1v = 2.0f * s_f1[buf][q * 8 + z];
                const float4 f2v = *reinterpret_cast<const float4*>(&s_f2[buf][q * 8 + a0]);
                v.x = f1v * f2v.x;
                v.y = f1v * f2v.y;
                v.z = f1v * f2v.z;
                v.w = f1v * f2v.w;
            }
            reinterpret_cast<float4*>(o)[idx4] = v;
        }
        // no trailing barrier: next iteration's phase-1 writes go to the other
        // buffer; the collective barriers B1/B2 of later iterations order the
        // same-buffer reuse (reads of buf complete before any wave re-passes
        // two barriers to write it again).
    }
}

extern "C" void kernel_launch(void* const* d_in, const int* in_sizes, int n_in,
                              void* d_out, int out_size, void* d_ws, size_t ws_size,
                              hipStream_t stream) {
    const float* coef = (const float*)d_in[0];
    float* out = (float*)d_out;
    // 16384 atoms / 8 per block = 2048 blocks (8 blocks/CU, fully resident)
    OrbitalAEVComputer_40492951667225_kernel<<<dim3(NCONF * NATOMS / APB), dim3(256), 0, stream>>>(coef, out);
}